// Round 6
// baseline (431.330 us; speedup 1.0000x reference)
//
#include <hip/hip_runtime.h>
#include <math.h>

// Problem dims
#define Mm 8
#define Bb 64
#define Ss 1024
#define Kk 256
#define Hh 8
#define HD 32
#define Ff 1024

typedef _Float16 f16x8 __attribute__((ext_vector_type(8)));
typedef float f32x4 __attribute__((ext_vector_type(4)));

// Workspace layout (float offsets), lifetimes disjoint where overlapped:
#define WS_Q      0u         // k1->k2, then FC (k5->k6)
#define WS_U      131072u    // k2->k3, then GATES at 262144
#define WS_QDB    1179648u   // k2->k3
#define WS_SC     1183744u   // k3->k4a, then HPART (k7a->k7b)
#define WS_WPART  5378048u   // k4a->k5 (4 x 1048576), then H1 (k6->k7a)
#define WS_FC     0u
#define WS_H1     5378048u
#define WS_GATES  262144u
#define WS_HPART  1183744u
// total 9572352 floats = 38.3 MB

// ---------------------------------------------------------------------------
// async global->LDS DMA, 16 B per lane. LDS dest is lane-contiguous (HW rule).
__device__ __forceinline__ void dma16(const float* g, float* l) {
  __builtin_amdgcn_global_load_lds(
      (const __attribute__((address_space(1))) unsigned int*)g,
      (__attribute__((address_space(3))) unsigned int*)l, 16, 0, 0);
}

// ctg tile: 64 rows x 32 k fp32, physical k-group p = g ^ (r&7).
// Fragment read: 2x ds_read_b128, banks spread over XOR coset -> <=2-way.
__device__ __forceinline__ f16x8 frag_ctg(const float* T, int r, int quad) {
  const int x = r & 7;
  const float4 a0 = *(const float4*)&T[r * 32 + (((2 * quad) ^ x) << 2)];
  const float4 a1 = *(const float4*)&T[r * 32 + (((2 * quad + 1) ^ x) << 2)];
  f16x8 f;
  f[0] = (_Float16)a0.x; f[1] = (_Float16)a0.y;
  f[2] = (_Float16)a0.z; f[3] = (_Float16)a0.w;
  f[4] = (_Float16)a1.x; f[5] = (_Float16)a1.y;
  f[6] = (_Float16)a1.z; f[7] = (_Float16)a1.w;
  return f;
}

// ctr tile: 32 k-rows x 64 cols fp32, physical group p = g ^ swz(kr).
// swz mixes kr's bit3 into bit1 so quads diverge mod-8 (bank wrap at 128B).
__device__ __forceinline__ int swz(int kr) {
  return (kr & 15) ^ ((kr >> 3) << 1);
}
__device__ __forceinline__ f16x8 frag_ctr(const float* T, int col, int quad) {
  const int g = col >> 2, c = col & 3;
  f16x8 f;
#pragma unroll
  for (int j = 0; j < 8; ++j) {
    const int kr = quad * 8 + j;
    f[j] = (_Float16)T[kr * 64 + ((g ^ swz(kr)) << 2) + c];
  }
  return f;
}

// ---------------------------------------------------------------------------
// K1: q = q0 @ Wq + bq        (M,B,K)
__global__ __launch_bounds__(256) void k1_qproj(
    const float* __restrict__ q0, const float* __restrict__ wq,
    const float* __restrict__ bq, float* __restrict__ qout) {
  __shared__ float q0s[8 * 260];
  const int m = blockIdx.x, b0 = blockIdx.y * 8, t = threadIdx.x;
#pragma unroll
  for (int j = 0; j < 8; ++j)
    q0s[j * 260 + t] = q0[(m * Bb + b0 + j) * Kk + t];
  __syncthreads();
  float acc[8];
  const float bias = bq[m * Kk + t];
#pragma unroll
  for (int j = 0; j < 8; ++j) acc[j] = bias;
  const float* wcol = wq + m * Kk * Kk + t;
  for (int k4 = 0; k4 < Kk / 4; ++k4) {
    const float w0 = wcol[(k4 * 4 + 0) * Kk];
    const float w1 = wcol[(k4 * 4 + 1) * Kk];
    const float w2 = wcol[(k4 * 4 + 2) * Kk];
    const float w3 = wcol[(k4 * 4 + 3) * Kk];
#pragma unroll
    for (int j = 0; j < 8; ++j) {
      const float4 qv = *(const float4*)&q0s[j * 260 + k4 * 4];
      acc[j] += qv.x * w0 + qv.y * w1 + qv.z * w2 + qv.w * w3;
    }
  }
#pragma unroll
  for (int j = 0; j < 8; ++j)
    qout[(m * Bb + b0 + j) * Kk + t] = acc[j];
}

// ---------------------------------------------------------------------------
// K2: u(m,b,h,k) = sum_d Wk[m,k,h*32+d] * q[m,b,h*32+d]
__global__ __launch_bounds__(256) void k2_uproj(
    const float* __restrict__ wk, const float* __restrict__ bk,
    const float* __restrict__ q, float* __restrict__ u,
    float* __restrict__ qdb) {
  __shared__ float qs[64 * 36];
  const int m = blockIdx.x, h = blockIdx.y, t = threadIdx.x;
#pragma unroll
  for (int p = 0; p < 8; ++p) {
    const int idx = p * 256 + t;
    const int d = idx & 31, b = idx >> 5;
    qs[b * 36 + d] = q[(m * Bb + b) * Kk + h * HD + d];
  }
  __syncthreads();
  float acc[64];
#pragma unroll
  for (int b = 0; b < 64; ++b) acc[b] = 0.f;
  const float* wrow = wk + (m * Kk + t) * Kk + h * HD;
#pragma unroll
  for (int d4 = 0; d4 < 8; ++d4) {
    const float4 w4 = *(const float4*)&wrow[d4 * 4];
#pragma unroll
    for (int b = 0; b < 64; ++b) {
      const float4 q4 = *(const float4*)&qs[b * 36 + d4 * 4];
      acc[b] += q4.x * w4.x + q4.y * w4.y + q4.z * w4.z + q4.w * w4.w;
    }
  }
  for (int b = 0; b < 64; ++b)
    u[((m * Bb + b) * Hh + h) * Kk + t] = acc[b];
  if (t < 64) {
    float s = 0.f;
#pragma unroll
    for (int d = 0; d < 32; ++d)
      s += qs[t * 36 + d] * bk[m * Kk + h * HD + d];
    qdb[(m * Bb + t) * Hh + h] = s;
  }
}

// ---------------------------------------------------------------------------
// K3 (MFMA + global_load_lds dbuf): scores = (key.u + qdb)/sqrt(32)
// grid (64, 16): (b, s-tile of 64). A=u ctg 64x32, B=key ctg 64x32, 8 chunks.
__global__ __launch_bounds__(256) void k3_scores(
    const float* __restrict__ key, const float* __restrict__ u,
    const float* __restrict__ qdb, float* __restrict__ sc) {
  __shared__ __attribute__((aligned(16))) float TA[2][2048];
  __shared__ __attribute__((aligned(16))) float TB[2][2048];
  __shared__ float qd[64];
  const int b = blockIdx.x, st0 = blockIdx.y * 64, t = threadIdx.x;
  const int w = t >> 6, lane = t & 63, quad = (t >> 4) & 3, l15 = t & 15;
  if (t < 64) qd[t] = qdb[((t >> 3) * Bb + b) * Hh + (t & 7)];

  auto dmaAB = [&](int c, int buf) {
#pragma unroll
    for (int j = 0; j < 2; ++j) {
      const int r = w * 16 + j * 8 + (lane >> 3);
      const int gp = (lane & 7) ^ (r & 7);
      dma16(u + (((r >> 3) * Bb + b) * Hh + (r & 7)) * Kk + c * 32 + gp * 4,
            &TA[buf][(w * 2 + j) * 256 + lane * 4]);
    }
#pragma unroll
    for (int j = 0; j < 2; ++j) {
      const int sr = w * 16 + j * 8 + (lane >> 3);
      const int gp = (lane & 7) ^ (sr & 7);
      dma16(key + (size_t)(st0 + sr) * (Bb * Kk) + b * Kk + c * 32 + gp * 4,
            &TB[buf][(w * 2 + j) * 256 + lane * 4]);
    }
  };

  f32x4 acc[4];
#pragma unroll
  for (int i = 0; i < 4; ++i) acc[i] = (f32x4){0.f, 0.f, 0.f, 0.f};
  dmaAB(0, 0);
  __syncthreads();
#pragma unroll
  for (int c = 0; c < 8; ++c) {
    if (c + 1 < 8) dmaAB(c + 1, (c + 1) & 1);
    const float* A = TA[c & 1];
    const float* B = TB[c & 1];
    const f16x8 af = frag_ctg(A, w * 16 + l15, quad);
#pragma unroll
    for (int sf = 0; sf < 4; ++sf) {
      const f16x8 bf = frag_ctg(B, sf * 16 + l15, quad);
      acc[sf] =
          __builtin_amdgcn_mfma_f32_16x16x32_f16(af, bf, acc[sf], 0, 0, 0);
    }
    __syncthreads();
  }
  const float scale = 0.17677669529663687f;  // 1/sqrt(32)
#pragma unroll
  for (int sf = 0; sf < 4; ++sf) {
    const int s = st0 + sf * 16 + l15;
#pragma unroll
    for (int r = 0; r < 4; ++r) {
      const int mh = w * 16 + quad * 4 + r;
      sc[(size_t)(((mh >> 3) * Bb + b) * Hh + (mh & 7)) * Ss + s] =
          (acc[sf][r] + qd[mh]) * scale;
    }
  }
}

// ---------------------------------------------------------------------------
// K3b: softmax over s per (m,b,h) + attn_weights mean-over-h, fused.
__global__ __launch_bounds__(256) void k3b_softmax(float* __restrict__ sc,
                                                   float* __restrict__ out) {
  __shared__ float rows[8 * 1024];
  const int m = blockIdx.x, b = blockIdx.y, t = threadIdx.x;
  const int w = t >> 6, lane = t & 63;
  const size_t base = (size_t)(m * Bb + b) * (Hh * Ss);
#pragma unroll
  for (int hh = 0; hh < 2; ++hh) {
    const int h = w * 2 + hh;
    float* g = sc + base + h * 1024;
    float4 v0 = *(const float4*)&g[lane * 4];
    float4 v1 = *(const float4*)&g[256 + lane * 4];
    float4 v2 = *(const float4*)&g[512 + lane * 4];
    float4 v3 = *(const float4*)&g[768 + lane * 4];
    float mx = fmaxf(fmaxf(fmaxf(v0.x, v0.y), fmaxf(v0.z, v0.w)),
                     fmaxf(fmaxf(v1.x, v1.y), fmaxf(v1.z, v1.w)));
    mx = fmaxf(mx, fmaxf(fmaxf(fmaxf(v2.x, v2.y), fmaxf(v2.z, v2.w)),
                         fmaxf(fmaxf(v3.x, v3.y), fmaxf(v3.z, v3.w))));
#pragma unroll
    for (int off = 32; off > 0; off >>= 1)
      mx = fmaxf(mx, __shfl_xor(mx, off, 64));
    v0.x = __expf(v0.x - mx); v0.y = __expf(v0.y - mx);
    v0.z = __expf(v0.z - mx); v0.w = __expf(v0.w - mx);
    v1.x = __expf(v1.x - mx); v1.y = __expf(v1.y - mx);
    v1.z = __expf(v1.z - mx); v1.w = __expf(v1.w - mx);
    v2.x = __expf(v2.x - mx); v2.y = __expf(v2.y - mx);
    v2.z = __expf(v2.z - mx); v2.w = __expf(v2.w - mx);
    v3.x = __expf(v3.x - mx); v3.y = __expf(v3.y - mx);
    v3.z = __expf(v3.z - mx); v3.w = __expf(v3.w - mx);
    float sm = v0.x + v0.y + v0.z + v0.w + v1.x + v1.y + v1.z + v1.w +
               v2.x + v2.y + v2.z + v2.w + v3.x + v3.y + v3.z + v3.w;
#pragma unroll
    for (int off = 32; off > 0; off >>= 1) sm += __shfl_xor(sm, off, 64);
    const float inv = 1.f / sm;
    v0.x *= inv; v0.y *= inv; v0.z *= inv; v0.w *= inv;
    v1.x *= inv; v1.y *= inv; v1.z *= inv; v1.w *= inv;
    v2.x *= inv; v2.y *= inv; v2.z *= inv; v2.w *= inv;
    v3.x *= inv; v3.y *= inv; v3.z *= inv; v3.w *= inv;
    *(float4*)&g[lane * 4] = v0;
    *(float4*)&g[256 + lane * 4] = v1;
    *(float4*)&g[512 + lane * 4] = v2;
    *(float4*)&g[768 + lane * 4] = v3;
    float* r = rows + h * 1024;
    *(float4*)&r[lane * 4] = v0;
    *(float4*)&r[256 + lane * 4] = v1;
    *(float4*)&r[512 + lane * 4] = v2;
    *(float4*)&r[768 + lane * 4] = v3;
  }
  __syncthreads();
#pragma unroll
  for (int p = 0; p < 4; ++p) {
    const int s = p * 256 + t;
    float sum = 0.f;
#pragma unroll
    for (int h = 0; h < 8; ++h) sum += rows[h * 1024 + s];
    out[131072u + (m * Bb + b) * Ss + s] = sum * 0.125f;
  }
}

// ---------------------------------------------------------------------------
// K4a (MFMA + DMA dbuf): partial w over s-quarter.
// grid (64, 4, 4): (b, ko of 64 k, sq of 256 s). A=aw ctg, B=value ctr, 8 chunks.
__global__ __launch_bounds__(256) void k4a_av(const float* __restrict__ value,
                                              const float* __restrict__ aw,
                                              float* __restrict__ wpart) {
  __shared__ __attribute__((aligned(16))) float TA[2][2048];
  __shared__ __attribute__((aligned(16))) float TB[2][2048];
  const int b = blockIdx.x, ko = blockIdx.y, sq = blockIdx.z, t = threadIdx.x;
  const int w = t >> 6, lane = t & 63, quad = (t >> 4) & 3, l15 = t & 15;

  auto dmaAB = [&](int c, int buf) {
#pragma unroll
    for (int j = 0; j < 2; ++j) {
      const int r = w * 16 + j * 8 + (lane >> 3);
      const int gp = (lane & 7) ^ (r & 7);
      dma16(aw + ((size_t)((r >> 3) * Bb + b) * Hh + (r & 7)) * Ss +
                sq * 256 + c * 32 + gp * 4,
            &TA[buf][(w * 2 + j) * 256 + lane * 4]);
    }
#pragma unroll
    for (int j = 0; j < 2; ++j) {
      const int kr = w * 8 + j * 4 + (lane >> 4);
      const int gp = (lane & 15) ^ swz(kr);
      dma16(value + (size_t)(sq * 256 + c * 32 + kr) * (Bb * Kk) + b * Kk +
                ko * 64 + gp * 4,
            &TB[buf][(w * 2 + j) * 256 + lane * 4]);
    }
  };

  f32x4 acc[4];
#pragma unroll
  for (int i = 0; i < 4; ++i) acc[i] = (f32x4){0.f, 0.f, 0.f, 0.f};
  dmaAB(0, 0);
  __syncthreads();
#pragma unroll
  for (int c = 0; c < 8; ++c) {
    if (c + 1 < 8) dmaAB(c + 1, (c + 1) & 1);
    const float* A = TA[c & 1];
    const float* B = TB[c & 1];
    const f16x8 af = frag_ctg(A, w * 16 + l15, quad);
#pragma unroll
    for (int nf = 0; nf < 4; ++nf) {
      const f16x8 bf = frag_ctr(B, nf * 16 + l15, quad);
      acc[nf] =
          __builtin_amdgcn_mfma_f32_16x16x32_f16(af, bf, acc[nf], 0, 0, 0);
    }
    __syncthreads();
  }
  float* wp = wpart + sq * 1048576u;
#pragma unroll
  for (int nf = 0; nf < 4; ++nf) {
    const int k = ko * 64 + nf * 16 + l15;
#pragma unroll
    for (int r = 0; r < 4; ++r) {
      const int mh = w * 16 + quad * 4 + r;
      wp[((size_t)((mh >> 3) * Bb + b) * Hh + (mh & 7)) * Kk + k] =
          acc[nf][r];
    }
  }
}

// ---------------------------------------------------------------------------
// K5: w = sum of 4 partials; ctx = w @ Wv_h + bv ; attn_out = ctx @ Wo + bo ;
//     fc_in = relu(concat). grid (8, 64) : (m, b)
__global__ __launch_bounds__(256) void k5_ctx(
    const float* __restrict__ wv, const float* __restrict__ bv,
    const float* __restrict__ wo, const float* __restrict__ bo,
    const float* __restrict__ s0in, const float* __restrict__ wpart,
    float* __restrict__ attn_out, float* __restrict__ fc) {
  __shared__ float wsh[2048];
  __shared__ float ctxs[256];
  const int m = blockIdx.x, b = blockIdx.y, t = threadIdx.x;
  const int base = (m * Bb + b) * (Hh * Kk);
#pragma unroll
  for (int p = 0; p < 8; ++p) {
    const int o = base + p * 256 + t;
    wsh[p * 256 + t] = wpart[o] + wpart[1048576u + o] + wpart[2097152u + o] +
                       wpart[3145728u + o];
  }
  __syncthreads();
  const int h = t >> 5;
  float acc = bv[m * Kk + t];
  const float* wvc = wv + m * Kk * Kk + t;
  for (int k4 = 0; k4 < 64; ++k4) {
    const float4 a4 = *(const float4*)&wsh[h * 256 + k4 * 4];
    acc += a4.x * wvc[(k4 * 4 + 0) * Kk] + a4.y * wvc[(k4 * 4 + 1) * Kk] +
           a4.z * wvc[(k4 * 4 + 2) * Kk] + a4.w * wvc[(k4 * 4 + 3) * Kk];
  }
  ctxs[t] = acc;
  __syncthreads();
  float acc2 = bo[m * Kk + t];
  const float* woc = wo + m * Kk * Kk + t;
  for (int k4 = 0; k4 < 64; ++k4) {
    const float4 c4 = *(const float4*)&ctxs[k4 * 4];
    acc2 += c4.x * woc[(k4 * 4 + 0) * Kk] + c4.y * woc[(k4 * 4 + 1) * Kk] +
            c4.z * woc[(k4 * 4 + 2) * Kk] + c4.w * woc[(k4 * 4 + 3) * Kk];
  }
  const int ob = (m * Bb + b) * Kk + t;
  attn_out[ob] = acc2;
  fc[(m * Bb + b) * 512 + t] = fmaxf(acc2, 0.f);
  fc[(m * Bb + b) * 512 + 256 + t] = fmaxf(s0in[ob], 0.f);
}

// ---------------------------------------------------------------------------
// K6 (MFMA + DMA dbuf): h1[head] = relu(fc_in @ W1[head] + b1[head])
// grid (16, 8, 8): (f-tile of 64, m, head). A=fc ctg, B=W1 ctr, 16 chunks.
__global__ __launch_bounds__(256) void k6_mlp1(
    const float* __restrict__ fc, const float* __restrict__ w1q,
    const float* __restrict__ w1k, const float* __restrict__ w1v,
    const float* __restrict__ w1s, const float* __restrict__ w1g,
    const float* __restrict__ b1q, const float* __restrict__ b1k,
    const float* __restrict__ b1v, const float* __restrict__ b1s,
    const float* __restrict__ b1g, float* __restrict__ h1) {
  __shared__ __attribute__((aligned(16))) float TA[2][2048];
  __shared__ __attribute__((aligned(16))) float TB[2][2048];
  const int ft = blockIdx.x, m = blockIdx.y, head = blockIdx.z,
            t = threadIdx.x;
  const float* w1;
  const float* b1;
  if (head == 0)      { w1 = w1q; b1 = b1q; }
  else if (head == 1) { w1 = w1k; b1 = b1k; }
  else if (head == 2) { w1 = w1v; b1 = b1v; }
  else if (head == 3) { w1 = w1s; b1 = b1s; }
  else {
    w1 = w1g + (size_t)(head - 4) * (Mm * 512 * Ff);
    b1 = b1g + (head - 4) * (Mm * Ff);
  }
  w1 += (size_t)m * 512 * Ff;
  b1 += m * Ff;
  const int w = t >> 6, lane = t & 63, quad = (t >> 4) & 3, l15 = t & 15;
  const float* fcm = fc + m * Bb * 512;

  auto dmaAB = [&](int c, int buf) {
#pragma unroll
    for (int j = 0; j < 2; ++j) {
      const int r = w * 16 + j * 8 + (lane >> 3);
      const int gp = (lane & 7) ^ (r & 7);
      dma16(fcm + r * 512 + c * 32 + gp * 4,
            &TA[buf][(w * 2 + j) * 256 + lane * 4]);
    }
#pragma unroll
    for (int j = 0; j < 2; ++j) {
      const int kr = w * 8 + j * 4 + (lane >> 4);
      const int gp = (lane & 15) ^ swz(kr);
      dma16(w1 + (size_t)(c * 32 + kr) * Ff + ft * 64 + gp * 4,
            &TB[buf][(w * 2 + j) * 256 + lane * 4]);
    }
  };

  f32x4 acc[4];
#pragma unroll
  for (int i = 0; i < 4; ++i) acc[i] = (f32x4){0.f, 0.f, 0.f, 0.f};
  dmaAB(0, 0);
  __syncthreads();
#pragma unroll
  for (int c = 0; c < 16; ++c) {
    if (c + 1 < 16) dmaAB(c + 1, (c + 1) & 1);
    const float* A = TA[c & 1];
    const float* B = TB[c & 1];
    const f16x8 bf = frag_ctr(B, w * 16 + l15, quad);
#pragma unroll
    for (int mt = 0; mt < 4; ++mt) {
      const f16x8 af = frag_ctg(A, mt * 16 + l15, quad);
      acc[mt] =
          __builtin_amdgcn_mfma_f32_16x16x32_f16(af, bf, acc[mt], 0, 0, 0);
    }
    __syncthreads();
  }
  const int f = ft * 64 + w * 16 + l15;
  const float bias = b1[f];
  float* hb = h1 + (size_t)((head * Mm + m) * Bb) * Ff + f;
#pragma unroll
  for (int mt = 0; mt < 4; ++mt) {
#pragma unroll
    for (int r = 0; r < 4; ++r) {
      const int bb = mt * 16 + quad * 4 + r;
      hb[(size_t)bb * Ff] = fmaxf(acc[mt][r] + bias, 0.f);
    }
  }
}

// ---------------------------------------------------------------------------
// K6b: gates(g,m,b) = sigmoid(h1[4+g,m,b,:] . g_w2[g,m,:] + g_b2[g,m])
__global__ __launch_bounds__(64) void k6b_gates(
    const float* __restrict__ h1, const float* __restrict__ gw2,
    const float* __restrict__ gb2, float* __restrict__ gates) {
  const int gm = blockIdx.x, b = blockIdx.y, t = threadIdx.x;
  const int g = gm >> 3, m = gm & 7;
  const float* hrow = h1 + (size_t)(((4 + g) * Mm + m) * Bb + b) * Ff;
  const float* wrow = gw2 + (g * Mm + m) * Ff;
  float s = 0.f;
#pragma unroll
  for (int i = 0; i < 16; ++i) s += hrow[t + i * 64] * wrow[t + i * 64];
  for (int off = 32; off > 0; off >>= 1) s += __shfl_down(s, off, 64);
  if (t == 0)
    gates[(g * Mm + m) * Bb + b] =
        1.f / (1.f + __expf(-(s + gb2[g * Mm + m])));
}

// ---------------------------------------------------------------------------
// K7a (MFMA + DMA dbuf): partial head outputs over f-quarter.
// grid (16, 8, 4): (ot + 4*fq, m, head). A=h1 ctg, B=w2 ctr, 8 chunks.
__global__ __launch_bounds__(256) void k7a_mlp2(
    const float* __restrict__ h1, const float* __restrict__ w2q,
    const float* __restrict__ w2k, const float* __restrict__ w2v,
    const float* __restrict__ w2s, float* __restrict__ hpart) {
  __shared__ __attribute__((aligned(16))) float TA[2][2048];
  __shared__ __attribute__((aligned(16))) float TB[2][2048];
  const int ot = blockIdx.x & 3, fq = blockIdx.x >> 2;
  const int m = blockIdx.y, head = blockIdx.z, t = threadIdx.x;
  const float* w2 =
      (head == 0) ? w2q : (head == 1) ? w2k : (head == 2) ? w2v : w2s;
  w2 += (size_t)m * Ff * Kk;
  const int w = t >> 6, lane = t & 63, quad = (t >> 4) & 3, l15 = t & 15;
  const float* hbase = h1 + (size_t)((head * Mm + m) * Bb) * Ff + fq * 256;

  auto dmaAB = [&](int c, int buf) {
#pragma unroll
    for (int j = 0; j < 2; ++j) {
      const int r = w * 16 + j * 8 + (lane >> 3);
      const int gp = (lane & 7) ^ (r & 7);
      dma16(hbase + (size_t)r * Ff + c * 32 + gp * 4,
            &TA[buf][(w * 2 + j) * 256 + lane * 4]);
    }
#pragma unroll
    for (int j = 0; j < 2; ++j) {
      const int kr = w * 8 + j * 4 + (lane >> 4);
      const int gp = (lane & 15) ^ swz(kr);
      dma16(w2 + (size_t)(fq * 256 + c * 32 + kr) * Kk + ot * 64 + gp * 4,
            &TB[buf][(w * 2 + j) * 256 + lane * 4]);
    }
  };

  f32x4 acc[4];
#pragma unroll
  for (int i = 0; i < 4; ++i) acc[i] = (f32x4){0.f, 0.f, 0.f, 0.f};
  dmaAB(0, 0);
  __syncthreads();
#pragma unroll
  for (int c = 0; c < 8; ++c) {
    if (c + 1 < 8) dmaAB(c + 1, (c + 1) & 1);
    const float* A = TA[c & 1];
    const float* B = TB[c & 1];
    const f16x8 bf = frag_ctr(B, w * 16 + l15, quad);
#pragma unroll
    for (int mt = 0; mt < 4; ++mt) {
      const f16x8 af = frag_ctg(A, mt * 16 + l15, quad);
      acc[mt] =
          __builtin_amdgcn_mfma_f32_16x16x32_f16(af, bf, acc[mt], 0, 0, 0);
    }
    __syncthreads();
  }
  const int o = ot * 64 + w * 16 + l15;
  float* hp = hpart + fq * 524288u + (size_t)((head * Mm + m) * Bb) * Kk + o;
#pragma unroll
  for (int mt = 0; mt < 4; ++mt) {
#pragma unroll
    for (int r = 0; r < 4; ++r) {
      const int bb = mt * 16 + quad * 4 + r;
      hp[(size_t)bb * Kk] = acc[mt][r];
    }
  }
}

// ---------------------------------------------------------------------------
// K7b: out = gate*tanh(relu(p0+p1+p2+p3+b2)) + (1-gate)*x0
__global__ __launch_bounds__(256) void k7b_final(
    const float* __restrict__ hpart, const float* __restrict__ gates,
    const float* __restrict__ b2q, const float* __restrict__ b2k,
    const float* __restrict__ b2v, const float* __restrict__ b2s,
    const float* __restrict__ q0, const float* __restrict__ k0,
    const float* __restrict__ v0, const float* __restrict__ s0,
    float* __restrict__ out) {
  const int idx = blockIdx.x * 256 + threadIdx.x;
  const int o = idx & 255;
  const int b = (idx >> 8) & 63;
  const int m = (idx >> 14) & 7;
  const int head = idx >> 17;
  const float* b2 = (head == 0) ? b2q : (head == 1) ? b2k
                    : (head == 2) ? b2v : b2s;
  const float* x0 = (head == 0) ? q0 : (head == 1) ? k0
                    : (head == 2) ? v0 : s0;
  const unsigned ooff = (head == 0) ? 786432u
                        : (head == 1) ? 917504u
                        : (head == 2) ? 1048576u : 655360u;
  float v = hpart[idx] + hpart[524288u + idx] + hpart[1048576u + idx] +
            hpart[1572864u + idx] + b2[m * Kk + o];
  v = tanhf(fmaxf(v, 0.f));
  const float g = gates[(head * Mm + m) * Bb + b];
  const float x = x0[(m * Bb + b) * Kk + o];
  out[ooff + (m * Bb + b) * Kk + o] = g * v + (1.f - g) * x;
}

// ---------------------------------------------------------------------------
extern "C" void kernel_launch(void* const* d_in, const int* in_sizes, int n_in,
                              void* d_out, int out_size, void* d_ws,
                              size_t ws_size, hipStream_t stream) {
  (void)in_sizes; (void)n_in; (void)out_size; (void)ws_size;
  const float* s0  = (const float*)d_in[0];
  const float* q0  = (const float*)d_in[1];
  const float* k0  = (const float*)d_in[2];
  const float* v0  = (const float*)d_in[3];
  const float* key = (const float*)d_in[4];
  const float* val = (const float*)d_in[5];
  const float* wq  = (const float*)d_in[6];
  const float* wk  = (const float*)d_in[7];
  const float* wv  = (const float*)d_in[8];
  const float* bqa = (const float*)d_in[9];
  const float* bka = (const float*)d_in[10];
  const float* bva = (const float*)d_in[11];
  const float* wo  = (const float*)d_in[12];
  const float* bo  = (const float*)d_in[13];
  const float* qw1 = (const float*)d_in[14];
  const float* qb1 = (const float*)d_in[15];
  const float* qw2 = (const float*)d_in[16];
  const float* qb2 = (const float*)d_in[17];
  const float* kw1 = (const float*)d_in[18];
  const float* kb1 = (const float*)d_in[19];
  const float* kw2 = (const float*)d_in[20];
  const float* kb2 = (const float*)d_in[21];
  const float* vw1 = (const float*)d_in[22];
  const float* vb1 = (const float*)d_in[23];
  const float* vw2 = (const float*)d_in[24];
  const float* vb2 = (const float*)d_in[25];
  const float* sw1 = (const float*)d_in[26];
  const float* sb1 = (const float*)d_in[27];
  const float* sw2 = (const float*)d_in[28];
  const float* sb2 = (const float*)d_in[29];
  const float* gw1 = (const float*)d_in[30];
  const float* gb1 = (const float*)d_in[31];
  const float* gw2 = (const float*)d_in[32];
  const float* gb2 = (const float*)d_in[33];
  float* ws  = (float*)d_ws;
  float* out = (float*)d_out;

  k1_qproj<<<dim3(8, 8), 256, 0, stream>>>(q0, wq, bqa, ws + WS_Q);
  k2_uproj<<<dim3(8, 8), 256, 0, stream>>>(wk, bka, ws + WS_Q, ws + WS_U,
                                           ws + WS_QDB);
  k3_scores<<<dim3(64, 16), 256, 0, stream>>>(key, ws + WS_U, ws + WS_QDB,
                                              ws + WS_SC);
  k3b_softmax<<<dim3(8, 64), 256, 0, stream>>>(ws + WS_SC, out);
  k4a_av<<<dim3(64, 4, 4), 256, 0, stream>>>(val, ws + WS_SC, ws + WS_WPART);
  k5_ctx<<<dim3(8, 64), 256, 0, stream>>>(wv, bva, wo, bo, s0, ws + WS_WPART,
                                          out, ws + WS_FC);
  k6_mlp1<<<dim3(16, 8, 8), 256, 0, stream>>>(ws + WS_FC, qw1, kw1, vw1, sw1,
                                              gw1, qb1, kb1, vb1, sb1, gb1,
                                              ws + WS_H1);
  k6b_gates<<<dim3(32, 64), 64, 0, stream>>>(ws + WS_H1, gw2, gb2,
                                             ws + WS_GATES);
  k7a_mlp2<<<dim3(16, 8, 4), 256, 0, stream>>>(ws + WS_H1, qw2, kw2, vw2, sw2,
                                               ws + WS_HPART);
  k7b_final<<<dim3(2048), 256, 0, stream>>>(ws + WS_HPART, ws + WS_GATES, qb2,
                                            kb2, vb2, sb2, q0, k0, v0, s0,
                                            out);
}